// Round 6
// baseline (407.524 us; speedup 1.0000x reference)
//
#include <hip/hip_runtime.h>

typedef __attribute__((ext_vector_type(8))) __bf16 bf16x8;
typedef __attribute__((ext_vector_type(4))) float f32x4;
typedef __attribute__((ext_vector_type(4))) unsigned uint4v;
typedef __attribute__((ext_vector_type(8))) unsigned short ushort8;

#define T_TOKENS 8192
#define K_DIM    4096
#define N_DIM    4096
#define NGRP     32
#define GS       128

__device__ __forceinline__ unsigned short f2bf(float f) {
  unsigned u = __builtin_bit_cast(unsigned, f);
  u += 0x7fffu + ((u >> 16) & 1u);   // round-to-nearest-even (inputs are finite)
  return (unsigned short)(u >> 16);
}

// packed f32 pair -> 2x bf16 (RNE), single HW instruction
__device__ __forceinline__ unsigned pk2(float lo, float hi) {
  unsigned r;
  asm("v_cvt_pk_bf16_f32 %0, %1, %2" : "=v"(r) : "v"(lo), "v"(hi));
  return r;
}

__device__ __forceinline__ f32x4 mfma16(bf16x8 a, bf16x8 b, f32x4 c) {
  return __builtin_amdgcn_mfma_f32_16x16x32_bf16(a, b, c, 0, 0, 0);
}

__device__ __forceinline__ void gload_lds16(const void* g, void* l) {
  __builtin_amdgcn_global_load_lds(
      (const __attribute__((address_space(1))) void*)g,
      (__attribute__((address_space(3))) void*)l, 16, 0, 0);
}

// ---------------- Kernel 1: fold rotation+codebook+norm into W_eff (bf16) ----
__global__ __launch_bounds__(256) void k_fold(const int* __restrict__ idxp,
                                              const float* __restrict__ cb,
                                              const float* __restrict__ norms,
                                              const float* __restrict__ rot,
                                              unsigned short* __restrict__ weff) {
  const int nt = blockIdx.x;   // n-tile (0..31)
  const int g  = blockIdx.y;   // group  (0..31)
  __shared__ unsigned short Rt[128][136];
  __shared__ unsigned short Wq[128][136];
  __shared__ float cbl[16];
  const int tid = threadIdx.x;
  if (tid < 16) cbl[tid] = cb[tid];

  { // stage R_g transposed into LDS as bf16
    const int j = tid >> 1, kh = (tid & 1) * 64;
    const float* rp = rot + ((size_t)g * 128 + j) * 128 + kh;
    #pragma unroll
    for (int c = 0; c < 64; c += 4) {
      float4 v = *reinterpret_cast<const float4*>(rp + c);
      Rt[kh + c + 0][j] = f2bf(v.x);
      Rt[kh + c + 1][j] = f2bf(v.y);
      Rt[kh + c + 2][j] = f2bf(v.z);
      Rt[kh + c + 3][j] = f2bf(v.w);
    }
  }
  __syncthreads();

  { // decode packed 4-bit codes -> bf16 codebook values
    const int nl = tid >> 1, hf = (tid & 1);
    const int* ip = idxp + ((size_t)(nt * 128 + nl)) * (K_DIM / 2) + g * 64 + hf * 32;
    #pragma unroll
    for (int c = 0; c < 32; c += 4) {
      int4 v = *reinterpret_cast<const int4*>(ip + c);
      int vv[4] = {v.x, v.y, v.z, v.w};
      #pragma unroll
      for (int q = 0; q < 4; ++q) {
        int b = vv[q] & 0xFF;
        Wq[nl][hf * 64 + (c + q) * 2 + 0] = f2bf(cbl[b & 0xF]);
        Wq[nl][hf * 64 + (c + q) * 2 + 1] = f2bf(cbl[(b >> 4) & 0xF]);
      }
    }
  }
  __syncthreads();

  const int w = tid >> 6, l = tid & 63;
  const int rl = l & 15, hi = l >> 4;
  f32x4 acc[2][8] = {};
  #pragma unroll
  for (int ks = 0; ks < 4; ++ks) {
    bf16x8 a0 = *(const bf16x8*)&Wq[w * 32 +  0 + rl][ks * 32 + hi * 8];
    bf16x8 a1 = *(const bf16x8*)&Wq[w * 32 + 16 + rl][ks * 32 + hi * 8];
    #pragma unroll
    for (int nc = 0; nc < 8; ++nc) {
      bf16x8 bfr = *(const bf16x8*)&Rt[nc * 16 + rl][ks * 32 + hi * 8];
      acc[0][nc] = mfma16(a0, bfr, acc[0][nc]);
      acc[1][nc] = mfma16(a1, bfr, acc[1][nc]);
    }
  }

  const float inv_scale = 0.088388347648318447f;  // 1/sqrt(128)
  #pragma unroll
  for (int m = 0; m < 2; ++m) {
    const int r0 = nt * 128 + w * 32 + m * 16 + hi * 4;
    float nv[4];
    #pragma unroll
    for (int r = 0; r < 4; ++r) nv[r] = norms[(size_t)(r0 + r) * NGRP + g] * inv_scale;
    #pragma unroll
    for (int nc = 0; nc < 8; ++nc) {
      #pragma unroll
      for (int r = 0; r < 4; ++r) {
        weff[(size_t)(r0 + r) * K_DIM + g * GS + nc * 16 + rl] = f2bf(acc[m][nc][r] * nv[r]);
      }
    }
  }
}

// ---------------- Kernel 2: 256x256 8-phase GEMM with fused A fp32->bf16 ----
// R2-exact schedule (16x16x32, m-quadrant phases, B hoisted to ph0/4, B staged
// via gload_lds at ph2,3/6,7). A is now read DIRECTLY from x (fp32): plain
// float4 loads issued at ph0 (first half) / ph1 (second half), converted with
// v_cvt_pk_bf16_f32 and ds_write_b128'd (same XOR swizzle) at the ph2/ph3
// tails into the opposite parity region. Compiler-inserted vmcnt for the
// float4 uses also FIFO-drains the older B gload_lds; lgkmcnt(0) before the
// ph3 barrier publishes the A writes. C stored nontemporal.
#define BAR   asm volatile("s_barrier" ::: "memory")
#define LGKM0 asm volatile("s_waitcnt lgkmcnt(0)" ::: "memory")

#define STG(gbase, koff, ldsoff) do { \
    gload_lds16((gbase) + (size_t)(koff), &lds[(ldsoff) + dst0]); \
    gload_lds16((gbase) + (size_t)(koff) + (size_t)64 * K_DIM, \
                &lds[(ldsoff) + dst0 + 4096]); \
  } while (0)

#define RD_B(PAR) { \
    const int bb = 32768 + (PAR) * 16384 + (wc >> 1) * 8192 + ((wc & 1) * 64 + rl) * 64; \
    _Pragma("unroll") \
    for (int n = 0; n < 4; ++n) { \
      bfr[n][0] = *(const bf16x8*)&lds[bb + n * 1024 + slot0]; \
      bfr[n][1] = *(const bf16x8*)&lds[bb + n * 1024 + slot1]; \
    } \
  }

#define RD_A(PAR, MQ) { \
    const int ab = (PAR) * 16384 + wr * 8192 + ((MQ) * 32 + rl) * 64; \
    af0 = *(const bf16x8*)&lds[ab + slot0]; \
    af1 = *(const bf16x8*)&lds[ab + slot1]; \
    af2 = *(const bf16x8*)&lds[ab + 1024 + slot0]; \
    af3 = *(const bf16x8*)&lds[ab + 1024 + slot1]; \
  }

#define MFMAQ(MQ) { \
    __builtin_amdgcn_s_setprio(1); \
    _Pragma("unroll") \
    for (int n = 0; n < 4; ++n) { \
      acc[(MQ)*2][n]     = mfma16(af1, bfr[n][1], \
                             mfma16(af0, bfr[n][0], acc[(MQ)*2][n])); \
      acc[(MQ)*2 + 1][n] = mfma16(af3, bfr[n][1], \
                             mfma16(af2, bfr[n][0], acc[(MQ)*2 + 1][n])); \
    } \
    __builtin_amdgcn_s_setprio(0); \
  }

// write 2 swizzled 16B slots (8 bf16 each) of row rA from 4 float4s
#define WRA2(PARD, I, fA, fB, fC, fD) { \
    uint4v u; \
    u.x = pk2(fA.x, fA.y); u.y = pk2(fA.z, fA.w); \
    u.z = pk2(fB.x, fB.y); u.w = pk2(fB.z, fB.w); \
    *(uint4v*)&lds[(PARD) * 16384 + rA * 64 + (((hA * 4 + (I) * 2 + 0) ^ r8a) << 3)] = u; \
    u.x = pk2(fC.x, fC.y); u.y = pk2(fC.z, fC.w); \
    u.z = pk2(fD.x, fD.y); u.w = pk2(fD.z, fD.w); \
    *(uint4v*)&lds[(PARD) * 16384 + rA * 64 + (((hA * 4 + (I) * 2 + 1) ^ r8a) << 3)] = u; \
  }

#define HALF(PAR, kAn, kB, BOFF) { \
    bf16x8 bfr[4][2]; bf16x8 af0, af1, af2, af3; \
    float4 a0, a1, a2, a3, a4, a5, a6, a7; \
    const float4* ap = reinterpret_cast<const float4*>(pax + (size_t)(kAn)); \
    /* ph0 */ \
    RD_B(PAR) RD_A(PAR, 0) \
    a0 = ap[0]; a1 = ap[1]; a2 = ap[2]; a3 = ap[3]; \
    BAR; MFMAQ(0) BAR; \
    /* ph1 */ \
    RD_A(PAR, 1) \
    a4 = ap[4]; a5 = ap[5]; a6 = ap[6]; a7 = ap[7]; \
    BAR; MFMAQ(1) BAR; \
    /* ph2 */ \
    RD_A(PAR, 2) \
    STG(pb, kB, BOFF); \
    BAR; MFMAQ(2) \
    WRA2((PAR) ^ 1, 0, a0, a1, a2, a3) \
    BAR; \
    /* ph3 */ \
    RD_A(PAR, 3) \
    STG(pb2, kB, (BOFF) + 8192); \
    BAR; MFMAQ(3) \
    WRA2((PAR) ^ 1, 1, a4, a5, a6, a7) \
    LGKM0; BAR; \
  }

__global__ __launch_bounds__(512) void k_gemm(const float* __restrict__ X,
                                              const unsigned short* __restrict__ Bw,
                                              float* __restrict__ C) {
  __shared__ unsigned short lds[65536];   // 128 KiB
  const int tid = threadIdx.x;
  const int l = tid & 63, w = tid >> 6;
  const int wr = w >> 2, wc = w & 3;      // 2M x 4N waves
  const int rl = l & 15, hi = l >> 4;

  // XCD-aware bijective swizzle (512 blocks, 512%8==0)
  const int bid = blockIdx.x;
  const int swz = (bid & 7) * 64 + (bid >> 3);
  const int brow = (swz >> 4) * 256;      // 32 m-tiles
  const int bcol = (swz & 15) * 256;      // 16 n-tiles

  // B staging: per-thread source with inverse swizzle, linear LDS dest
  const int row0 = tid >> 3;                                // 0..63
  const int gc = ((tid & 7) ^ (row0 & 7)) * 8;              // pre-swizzled col
  const unsigned short* pb  = Bw + (size_t)(bcol + row0) * K_DIM + gc;
  const unsigned short* pb2 = pb + (size_t)128 * K_DIM;
  const int dst0 = tid * 8;

  // A source: fp32 x, one row + 32-col half per thread
  const int rA = tid >> 1, hA = tid & 1;
  const int r8a = rA & 7;
  const float* pax = X + (size_t)(brow + rA) * K_DIM + hA * 32;

  // swizzled ds_read slot offsets (ushort units; row&7 == rl&7 for our rows)
  const int rb7 = rl & 7;
  const int slot0 = ((0 + hi) ^ rb7) << 3;   // k-slot 0
  const int slot1 = ((4 + hi) ^ rb7) << 3;   // k-slot 1

  f32x4 acc[8][4] = {};

  // ---- prologue: A(0) via regs+cvt, B(0), B(1) via gload_lds ----
  {
    const float4* ap = reinterpret_cast<const float4*>(pax);
    float4 a0 = ap[0], a1 = ap[1], a2 = ap[2], a3 = ap[3];
    float4 a4 = ap[4], a5 = ap[5], a6 = ap[6], a7 = ap[7];
    STG(pb,  0,  32768);                  // B(0).h0
    STG(pb2, 0,  32768 + 8192);           // B(0).h1
    STG(pb,  64, 32768 + 16384);          // B(1).h0
    STG(pb2, 64, 32768 + 16384 + 8192);   // B(1).h1
    asm volatile("s_waitcnt vmcnt(4)" ::: "memory");  // A(0)+B(0) done, B(1) in flight
    WRA2(0, 0, a0, a1, a2, a3)
    WRA2(0, 1, a4, a5, a6, a7)
    LGKM0; BAR;
  }

  for (int it = 0; it < 32; ++it) {
    const int k0  = it * 128;
    const int kA1 = k0 + 64;                      // A cols of tile 2it+1
    const int kN0 = (k0 + 128) & (K_DIM - 1);     // tile 2it+2 (wrapped at end)
    const int kN1 = (k0 + 192) & (K_DIM - 1);     // tile 2it+3
    HALF(0, kA1, kN0, 32768)                      // compute tile 2it
    HALF(1, kN0, kN1, 32768 + 16384)              // compute tile 2it+1
  }

  #pragma unroll
  for (int m = 0; m < 8; ++m) {
    const int row = brow + wr * 128 + m * 16 + hi * 4;
    #pragma unroll
    for (int n = 0; n < 4; ++n) {
      const int col = bcol + wc * 64 + n * 16 + rl;
      #pragma unroll
      for (int r = 0; r < 4; ++r)
        __builtin_nontemporal_store(acc[m][n][r], &C[(size_t)(row + r) * N_DIM + col]);
    }
  }
}

extern "C" void kernel_launch(void* const* d_in, const int* in_sizes, int n_in,
                              void* d_out, int out_size, void* d_ws, size_t ws_size,
                              hipStream_t stream) {
  const float* x     = (const float*)d_in[0];
  const int*   idxp  = (const int*)d_in[1];
  const float* cb    = (const float*)d_in[2];
  const float* norms = (const float*)d_in[3];
  const float* rot   = (const float*)d_in[4];
  float* out = (float*)d_out;

  unsigned short* weff = (unsigned short*)d_ws;   // 32 MiB

  k_fold<<<dim3(32, 32), 256, 0, stream>>>(idxp, cb, norms, rot, weff);
  k_gemm<<<512, 512, 0, stream>>>(x, weff, out);
}

// Round 7
// 285.800 us; speedup vs baseline: 1.4259x; 1.4259x over previous
//
#include <hip/hip_runtime.h>

typedef __attribute__((ext_vector_type(8))) __bf16 bf16x8;
typedef __attribute__((ext_vector_type(4))) float f32x4;
typedef __attribute__((ext_vector_type(8))) unsigned short ushort8;

#define T_TOKENS 8192
#define K_DIM    4096
#define N_DIM    4096
#define NGRP     32
#define GS       128

__device__ __forceinline__ unsigned short f2bf(float f) {
  unsigned u = __builtin_bit_cast(unsigned, f);
  u += 0x7fffu + ((u >> 16) & 1u);   // round-to-nearest-even (inputs are finite)
  return (unsigned short)(u >> 16);
}

__device__ __forceinline__ f32x4 mfma16(bf16x8 a, bf16x8 b, f32x4 c) {
  return __builtin_amdgcn_mfma_f32_16x16x32_bf16(a, b, c, 0, 0, 0);
}

__device__ __forceinline__ void gload_lds16(const void* g, void* l) {
  __builtin_amdgcn_global_load_lds(
      (const __attribute__((address_space(1))) void*)g,
      (__attribute__((address_space(3))) void*)l, 16, 0, 0);
}

// ---------------- Kernel 1: fused convert (x->bf16) + fold (W_eff) ----------
// Blocks 0..1023: grid-stride fp32->bf16 convert of x.
// Blocks 1024..2047: per-(n-tile, group) fold of codebook+rotation+norm.
__global__ __launch_bounds__(256) void k_prep(const float* __restrict__ x,
                                              unsigned short* __restrict__ xb,
                                              const int* __restrict__ idxp,
                                              const float* __restrict__ cb,
                                              const float* __restrict__ norms,
                                              const float* __restrict__ rot,
                                              unsigned short* __restrict__ weff) {
  __shared__ unsigned short Rt[128][136];
  __shared__ unsigned short Wq[128][136];
  __shared__ float cbl[16];
  const int tid = threadIdx.x;

  if (blockIdx.x < 1024) {  // ---- convert part ----
    const int n8 = (T_TOKENS * K_DIM) / 8;
    int i = blockIdx.x * 256 + tid;
    const int stride = 1024 * 256;
    for (; i < n8; i += stride) {
      const float4* p = reinterpret_cast<const float4*>(x) + (size_t)i * 2;
      float4 v0 = p[0], v1 = p[1];
      ushort8 o;
      o[0] = f2bf(v0.x); o[1] = f2bf(v0.y); o[2] = f2bf(v0.z); o[3] = f2bf(v0.w);
      o[4] = f2bf(v1.x); o[5] = f2bf(v1.y); o[6] = f2bf(v1.z); o[7] = f2bf(v1.w);
      *reinterpret_cast<ushort8*>(xb + (size_t)i * 8) = o;
    }
    return;
  }

  // ---- fold part ----
  const int v = blockIdx.x - 1024;
  const int nt = v & 31;   // n-tile (0..31)
  const int g  = v >> 5;   // group  (0..31)
  if (tid < 16) cbl[tid] = cb[tid];

  { // stage R_g transposed into LDS as bf16
    const int j = tid >> 1, kh = (tid & 1) * 64;
    const float* rp = rot + ((size_t)g * 128 + j) * 128 + kh;
    #pragma unroll
    for (int c = 0; c < 64; c += 4) {
      float4 vv = *reinterpret_cast<const float4*>(rp + c);
      Rt[kh + c + 0][j] = f2bf(vv.x);
      Rt[kh + c + 1][j] = f2bf(vv.y);
      Rt[kh + c + 2][j] = f2bf(vv.z);
      Rt[kh + c + 3][j] = f2bf(vv.w);
    }
  }
  __syncthreads();

  { // decode packed 4-bit codes -> bf16 codebook values
    const int nl = tid >> 1, hf = (tid & 1);
    const int* ip = idxp + ((size_t)(nt * 128 + nl)) * (K_DIM / 2) + g * 64 + hf * 32;
    #pragma unroll
    for (int c = 0; c < 32; c += 4) {
      int4 vv = *reinterpret_cast<const int4*>(ip + c);
      int va[4] = {vv.x, vv.y, vv.z, vv.w};
      #pragma unroll
      for (int q = 0; q < 4; ++q) {
        int b = va[q] & 0xFF;
        Wq[nl][hf * 64 + (c + q) * 2 + 0] = f2bf(cbl[b & 0xF]);
        Wq[nl][hf * 64 + (c + q) * 2 + 1] = f2bf(cbl[(b >> 4) & 0xF]);
      }
    }
  }
  __syncthreads();

  const int w = tid >> 6, l = tid & 63;
  const int rl = l & 15, hi = l >> 4;
  f32x4 acc[2][8] = {};
  #pragma unroll
  for (int ks = 0; ks < 4; ++ks) {
    bf16x8 a0 = *(const bf16x8*)&Wq[w * 32 +  0 + rl][ks * 32 + hi * 8];
    bf16x8 a1 = *(const bf16x8*)&Wq[w * 32 + 16 + rl][ks * 32 + hi * 8];
    #pragma unroll
    for (int nc = 0; nc < 8; ++nc) {
      bf16x8 bfr = *(const bf16x8*)&Rt[nc * 16 + rl][ks * 32 + hi * 8];
      acc[0][nc] = mfma16(a0, bfr, acc[0][nc]);
      acc[1][nc] = mfma16(a1, bfr, acc[1][nc]);
    }
  }

  const float inv_scale = 0.088388347648318447f;  // 1/sqrt(128)
  #pragma unroll
  for (int m = 0; m < 2; ++m) {
    const int r0 = nt * 128 + w * 32 + m * 16 + hi * 4;
    float nv[4];
    #pragma unroll
    for (int r = 0; r < 4; ++r) nv[r] = norms[(size_t)(r0 + r) * NGRP + g] * inv_scale;
    #pragma unroll
    for (int nc = 0; nc < 8; ++nc) {
      #pragma unroll
      for (int r = 0; r < 4; ++r) {
        weff[(size_t)(r0 + r) * K_DIM + g * GS + nc * 16 + rl] = f2bf(acc[m][nc][r] * nv[r]);
      }
    }
  }
}

// ---------------- Kernel 2: 256x256 8-phase GEMM (R2-exact schedule) --------
// BM=BN=256, BK=64, 512 threads = 8 waves (2M x 4N), per-wave C = 128x64.
// LDS 128 KiB: A[parity][half][128][64] + B[parity][half][128][64], bf16,
// XOR-swizzled (byte ^= (row&7)<<4) via pre-swizzled global source (linear
// gload_lds dest) + swizzled ds_read. One half-tile staged per phase,
// counted vmcnt(4) at phase tails 3 and 7 only.
// Only change vs R2: XCD block remap uses 8x8 tile chunks per XCD
// (was 4x16 strips) to cut cross-XCD B refetch: FETCH pred 315->~260 MB.
#define VMW asm volatile("s_waitcnt vmcnt(4)" ::: "memory")
#define NOW ((void)0)

#define STG(gbase, koff, ldsoff) do { \
    gload_lds16((gbase) + (size_t)(koff), &lds[(ldsoff) + dst0]); \
    gload_lds16((gbase) + (size_t)(koff) + (size_t)64 * K_DIM, \
                &lds[(ldsoff) + dst0 + 4096]); \
  } while (0)

#define PHASE(qq, PAR, TAIL, ...) { \
    if ((qq) == 0) { \
      const int bb = 32768 + (PAR) * 16384 + (wc >> 1) * 8192 + ((wc & 1) * 64 + rl) * 64; \
      _Pragma("unroll") \
      for (int n = 0; n < 4; ++n) { \
        bfr[n][0] = *(const bf16x8*)&lds[bb + n * 1024 + slot0]; \
        bfr[n][1] = *(const bf16x8*)&lds[bb + n * 1024 + slot1]; \
      } \
    } \
    { const int ab = (PAR) * 16384 + wr * 8192 + ((qq) * 32 + rl) * 64; \
      af00 = *(const bf16x8*)&lds[ab + slot0]; \
      af01 = *(const bf16x8*)&lds[ab + slot1]; \
      af10 = *(const bf16x8*)&lds[ab + 1024 + slot0]; \
      af11 = *(const bf16x8*)&lds[ab + 1024 + slot1]; } \
    __VA_ARGS__; \
    asm volatile("s_barrier" ::: "memory"); \
    __builtin_amdgcn_s_setprio(1); \
    _Pragma("unroll") \
    for (int n = 0; n < 4; ++n) { \
      acc[(qq)*2][n]     = mfma16(af00, bfr[n][0], acc[(qq)*2][n]); \
      acc[(qq)*2][n]     = mfma16(af01, bfr[n][1], acc[(qq)*2][n]); \
      acc[(qq)*2 + 1][n] = mfma16(af10, bfr[n][0], acc[(qq)*2 + 1][n]); \
      acc[(qq)*2 + 1][n] = mfma16(af11, bfr[n][1], acc[(qq)*2 + 1][n]); \
    } \
    __builtin_amdgcn_s_setprio(0); \
    TAIL; \
    asm volatile("s_barrier" ::: "memory"); \
  }

__global__ __launch_bounds__(512) void k_gemm(const unsigned short* __restrict__ A,
                                              const unsigned short* __restrict__ Bw,
                                              float* __restrict__ C) {
  __shared__ unsigned short lds[65536];   // 128 KiB
  const int tid = threadIdx.x;
  const int l = tid & 63, w = tid >> 6;
  const int wr = w >> 2, wc = w & 3;      // 2M x 4N waves
  const int rl = l & 15, hi = l >> 4;

  // XCD-aware remap: 512 blocks on a 32x16 tile grid; each XCD (bid&7) owns
  // an 8x8 tile chunk (A 16MB + B 16MB per XCD). Bijective: xcd in [0,8),
  // j in [0,64) -> chunk (xcd>>1, xcd&1), intra-chunk (j>>3, j&7).
  const int bid = blockIdx.x;
  const int xcd = bid & 7, j = bid >> 3;
  const int brow = ((xcd >> 1) * 8 + (j >> 3)) * 256;   // 32 m-tiles
  const int bcol = ((xcd & 1) * 8 + (j & 7)) * 256;     // 16 n-tiles

  // staging: per-thread source with inverse swizzle, linear LDS dest
  const int row0 = tid >> 3;                                // 0..63
  const int gc = ((tid & 7) ^ (row0 & 7)) * 8;              // pre-swizzled col
  const unsigned short* pa  = A  + (size_t)(brow + row0) * K_DIM + gc;
  const unsigned short* pa2 = pa + (size_t)128 * K_DIM;
  const unsigned short* pb  = Bw + (size_t)(bcol + row0) * K_DIM + gc;
  const unsigned short* pb2 = pb + (size_t)128 * K_DIM;
  const int dst0 = tid * 8;

  // swizzled ds_read slot offsets (ushort units; row&7 == rl&7 for our rows)
  const int rb7 = rl & 7;
  const int slot0 = ((0 + hi) ^ rb7) << 3;   // k-slot 0
  const int slot1 = ((4 + hi) ^ rb7) << 3;   // k-slot 1

  f32x4 acc[8][4] = {};

  // ---- prologue: stage B(0), A(0), B(1) ----
  STG(pb,  0,  32768);           // B(0).h0
  STG(pb2, 0,  32768 + 8192);    // B(0).h1
  STG(pa,  0,  0);               // A(0).h0
  STG(pa2, 0,  8192);            // A(0).h1
  STG(pb,  64, 32768 + 16384);          // B(1).h0
  STG(pb2, 64, 32768 + 16384 + 8192);   // B(1).h1
  asm volatile("s_waitcnt vmcnt(4)" ::: "memory");
  asm volatile("s_barrier" ::: "memory");

  for (int it = 0; it < 32; ++it) {
    const int k0  = it * 128;
    const int kA1 = k0 + 64;                      // tile 2it+1
    const int kN0 = (k0 + 128) & (K_DIM - 1);     // tile 2it+2 (wrapped at end)
    const int kN1 = (k0 + 192) & (K_DIM - 1);     // tile 2it+3
    bf16x8 bfr[4][2];
    bf16x8 af00, af01, af10, af11;
    PHASE(0, 0, NOW, STG(pa,  kA1, 16384))                 // stage A(2it+1).h0
    PHASE(1, 0, NOW, STG(pa2, kA1, 16384 + 8192))          // A(2it+1).h1
    PHASE(2, 0, NOW, STG(pb,  kN0, 32768))                 // B(2it+2).h0
    PHASE(3, 0, VMW, STG(pb2, kN0, 32768 + 8192))          // B(2it+2).h1
    PHASE(0, 1, NOW, STG(pa,  kN0, 0))                     // A(2it+2).h0
    PHASE(1, 1, NOW, STG(pa2, kN0, 8192))                  // A(2it+2).h1
    PHASE(2, 1, NOW, STG(pb,  kN1, 32768 + 16384))         // B(2it+3).h0
    PHASE(3, 1, VMW, STG(pb2, kN1, 32768 + 16384 + 8192))  // B(2it+3).h1
  }

  #pragma unroll
  for (int m = 0; m < 8; ++m) {
    const int row = brow + wr * 128 + m * 16 + hi * 4;
    #pragma unroll
    for (int n = 0; n < 4; ++n) {
      const int col = bcol + wc * 64 + n * 16 + rl;
      #pragma unroll
      for (int r = 0; r < 4; ++r)
        C[(size_t)(row + r) * N_DIM + col] = acc[m][n][r];
    }
  }
}

extern "C" void kernel_launch(void* const* d_in, const int* in_sizes, int n_in,
                              void* d_out, int out_size, void* d_ws, size_t ws_size,
                              hipStream_t stream) {
  const float* x     = (const float*)d_in[0];
  const int*   idxp  = (const int*)d_in[1];
  const float* cb    = (const float*)d_in[2];
  const float* norms = (const float*)d_in[3];
  const float* rot   = (const float*)d_in[4];
  float* out = (float*)d_out;

  unsigned short* xb   = (unsigned short*)d_ws;                              // 64 MiB
  unsigned short* weff = (unsigned short*)((char*)d_ws + (size_t)67108864);  // 32 MiB

  k_prep<<<2048, 256, 0, stream>>>(x, xb, idxp, cb, norms, rot, weff);
  k_gemm<<<512, 512, 0, stream>>>(xb, weff, out);
}

// Round 8
// 282.791 us; speedup vs baseline: 1.4411x; 1.0106x over previous
//
#include <hip/hip_runtime.h>

typedef __attribute__((ext_vector_type(8))) __bf16 bf16x8;
typedef __attribute__((ext_vector_type(4))) float f32x4;
typedef __attribute__((ext_vector_type(8))) unsigned short ushort8;

#define T_TOKENS 8192
#define K_DIM    4096
#define N_DIM    4096
#define NGRP     32
#define GS       128

__device__ __forceinline__ unsigned short f2bf(float f) {
  unsigned u = __builtin_bit_cast(unsigned, f);
  u += 0x7fffu + ((u >> 16) & 1u);   // round-to-nearest-even (inputs are finite)
  return (unsigned short)(u >> 16);
}

__device__ __forceinline__ f32x4 mfma16(bf16x8 a, bf16x8 b, f32x4 c) {
  return __builtin_amdgcn_mfma_f32_16x16x32_bf16(a, b, c, 0, 0, 0);
}

__device__ __forceinline__ void gload_lds16(const void* g, void* l) {
  __builtin_amdgcn_global_load_lds(
      (const __attribute__((address_space(1))) void*)g,
      (__attribute__((address_space(3))) void*)l, 16, 0, 0);
}

// ---------------- Kernel 1: fused convert (x->bf16) + fold (W_eff) ----------
// Blocks 0..1023: grid-stride fp32->bf16 convert of x.
// Blocks 1024..2047: per-(n-tile, group) fold of codebook+rotation+norm.
__global__ __launch_bounds__(256) void k_prep(const float* __restrict__ x,
                                              unsigned short* __restrict__ xb,
                                              const int* __restrict__ idxp,
                                              const float* __restrict__ cb,
                                              const float* __restrict__ norms,
                                              const float* __restrict__ rot,
                                              unsigned short* __restrict__ weff) {
  __shared__ unsigned short Rt[128][136];
  __shared__ unsigned short Wq[128][136];
  __shared__ float cbl[16];
  const int tid = threadIdx.x;

  if (blockIdx.x < 1024) {  // ---- convert part ----
    const int n8 = (T_TOKENS * K_DIM) / 8;
    int i = blockIdx.x * 256 + tid;
    const int stride = 1024 * 256;
    for (; i < n8; i += stride) {
      const float4* p = reinterpret_cast<const float4*>(x) + (size_t)i * 2;
      float4 v0 = p[0], v1 = p[1];
      ushort8 o;
      o[0] = f2bf(v0.x); o[1] = f2bf(v0.y); o[2] = f2bf(v0.z); o[3] = f2bf(v0.w);
      o[4] = f2bf(v1.x); o[5] = f2bf(v1.y); o[6] = f2bf(v1.z); o[7] = f2bf(v1.w);
      *reinterpret_cast<ushort8*>(xb + (size_t)i * 8) = o;
    }
    return;
  }

  // ---- fold part ----
  const int v = blockIdx.x - 1024;
  const int nt = v & 31;   // n-tile (0..31)
  const int g  = v >> 5;   // group  (0..31)
  if (tid < 16) cbl[tid] = cb[tid];

  { // stage R_g transposed into LDS as bf16
    const int j = tid >> 1, kh = (tid & 1) * 64;
    const float* rp = rot + ((size_t)g * 128 + j) * 128 + kh;
    #pragma unroll
    for (int c = 0; c < 64; c += 4) {
      float4 vv = *reinterpret_cast<const float4*>(rp + c);
      Rt[kh + c + 0][j] = f2bf(vv.x);
      Rt[kh + c + 1][j] = f2bf(vv.y);
      Rt[kh + c + 2][j] = f2bf(vv.z);
      Rt[kh + c + 3][j] = f2bf(vv.w);
    }
  }
  __syncthreads();

  { // decode packed 4-bit codes -> bf16 codebook values
    const int nl = tid >> 1, hf = (tid & 1);
    const int* ip = idxp + ((size_t)(nt * 128 + nl)) * (K_DIM / 2) + g * 64 + hf * 32;
    #pragma unroll
    for (int c = 0; c < 32; c += 4) {
      int4 vv = *reinterpret_cast<const int4*>(ip + c);
      int va[4] = {vv.x, vv.y, vv.z, vv.w};
      #pragma unroll
      for (int q = 0; q < 4; ++q) {
        int b = va[q] & 0xFF;
        Wq[nl][hf * 64 + (c + q) * 2 + 0] = f2bf(cbl[b & 0xF]);
        Wq[nl][hf * 64 + (c + q) * 2 + 1] = f2bf(cbl[(b >> 4) & 0xF]);
      }
    }
  }
  __syncthreads();

  const int w = tid >> 6, l = tid & 63;
  const int rl = l & 15, hi = l >> 4;
  f32x4 acc[2][8] = {};
  #pragma unroll
  for (int ks = 0; ks < 4; ++ks) {
    bf16x8 a0 = *(const bf16x8*)&Wq[w * 32 +  0 + rl][ks * 32 + hi * 8];
    bf16x8 a1 = *(const bf16x8*)&Wq[w * 32 + 16 + rl][ks * 32 + hi * 8];
    #pragma unroll
    for (int nc = 0; nc < 8; ++nc) {
      bf16x8 bfr = *(const bf16x8*)&Rt[nc * 16 + rl][ks * 32 + hi * 8];
      acc[0][nc] = mfma16(a0, bfr, acc[0][nc]);
      acc[1][nc] = mfma16(a1, bfr, acc[1][nc]);
    }
  }

  const float inv_scale = 0.088388347648318447f;  // 1/sqrt(128)
  #pragma unroll
  for (int m = 0; m < 2; ++m) {
    const int r0 = nt * 128 + w * 32 + m * 16 + hi * 4;
    float nv[4];
    #pragma unroll
    for (int r = 0; r < 4; ++r) nv[r] = norms[(size_t)(r0 + r) * NGRP + g] * inv_scale;
    #pragma unroll
    for (int nc = 0; nc < 8; ++nc) {
      #pragma unroll
      for (int r = 0; r < 4; ++r) {
        weff[(size_t)(r0 + r) * K_DIM + g * GS + nc * 16 + rl] = f2bf(acc[m][nc][r] * nv[r]);
      }
    }
  }
}

// ---------------- Kernel 2: 256x256 8-phase GEMM (R2-exact schedule) --------
// BM=BN=256, BK=64, 512 threads = 8 waves (2M x 4N), per-wave C = 128x64.
// LDS 128 KiB: A[parity][half][128][64] + B[parity][half][128][64], bf16,
// XOR-swizzled (byte ^= (row&7)<<4) via pre-swizzled global source (linear
// gload_lds dest) + swizzled ds_read. One half-tile staged per phase,
// counted vmcnt(4) at phase tails 3 and 7 only.
// Only change vs R2: XCD block remap uses 8x8 tile chunks per XCD
// (was 4x16 strips) to cut cross-XCD B refetch: FETCH pred 315->~260 MB.
#define VMW asm volatile("s_waitcnt vmcnt(4)" ::: "memory")
#define NOW ((void)0)

#define STG(gbase, koff, ldsoff) do { \
    gload_lds16((gbase) + (size_t)(koff), &lds[(ldsoff) + dst0]); \
    gload_lds16((gbase) + (size_t)(koff) + (size_t)64 * K_DIM, \
                &lds[(ldsoff) + dst0 + 4096]); \
  } while (0)

#define PHASE(qq, PAR, TAIL, ...) { \
    if ((qq) == 0) { \
      const int bb = 32768 + (PAR) * 16384 + (wc >> 1) * 8192 + ((wc & 1) * 64 + rl) * 64; \
      _Pragma("unroll") \
      for (int n = 0; n < 4; ++n) { \
        bfr[n][0] = *(const bf16x8*)&lds[bb + n * 1024 + slot0]; \
        bfr[n][1] = *(const bf16x8*)&lds[bb + n * 1024 + slot1]; \
      } \
    } \
    { const int ab = (PAR) * 16384 + wr * 8192 + ((qq) * 32 + rl) * 64; \
      af00 = *(const bf16x8*)&lds[ab + slot0]; \
      af01 = *(const bf16x8*)&lds[ab + slot1]; \
      af10 = *(const bf16x8*)&lds[ab + 1024 + slot0]; \
      af11 = *(const bf16x8*)&lds[ab + 1024 + slot1]; } \
    __VA_ARGS__; \
    asm volatile("s_barrier" ::: "memory"); \
    __builtin_amdgcn_s_setprio(1); \
    _Pragma("unroll") \
    for (int n = 0; n < 4; ++n) { \
      acc[(qq)*2][n]     = mfma16(af00, bfr[n][0], acc[(qq)*2][n]); \
      acc[(qq)*2][n]     = mfma16(af01, bfr[n][1], acc[(qq)*2][n]); \
      acc[(qq)*2 + 1][n] = mfma16(af10, bfr[n][0], acc[(qq)*2 + 1][n]); \
      acc[(qq)*2 + 1][n] = mfma16(af11, bfr[n][1], acc[(qq)*2 + 1][n]); \
    } \
    __builtin_amdgcn_s_setprio(0); \
    TAIL; \
    asm volatile("s_barrier" ::: "memory"); \
  }

__global__ __launch_bounds__(512) void k_gemm(const unsigned short* __restrict__ A,
                                              const unsigned short* __restrict__ Bw,
                                              float* __restrict__ C) {
  __shared__ unsigned short lds[65536];   // 128 KiB
  const int tid = threadIdx.x;
  const int l = tid & 63, w = tid >> 6;
  const int wr = w >> 2, wc = w & 3;      // 2M x 4N waves
  const int rl = l & 15, hi = l >> 4;

  // XCD-aware remap: 512 blocks on a 32x16 tile grid; each XCD (bid&7) owns
  // an 8x8 tile chunk (A 16MB + B 16MB per XCD). Bijective: xcd in [0,8),
  // j in [0,64) -> chunk (xcd>>1, xcd&1), intra-chunk (j>>3, j&7).
  const int bid = blockIdx.x;
  const int xcd = bid & 7, j = bid >> 3;
  const int brow = ((xcd >> 1) * 8 + (j >> 3)) * 256;   // 32 m-tiles
  const int bcol = ((xcd & 1) * 8 + (j & 7)) * 256;     // 16 n-tiles

  // staging: per-thread source with inverse swizzle, linear LDS dest
  const int row0 = tid >> 3;                                // 0..63
  const int gc = ((tid & 7) ^ (row0 & 7)) * 8;              // pre-swizzled col
  const unsigned short* pa  = A  + (size_t)(brow + row0) * K_DIM + gc;
  const unsigned short* pa2 = pa + (size_t)128 * K_DIM;
  const unsigned short* pb  = Bw + (size_t)(bcol + row0) * K_DIM + gc;
  const unsigned short* pb2 = pb + (size_t)128 * K_DIM;
  const int dst0 = tid * 8;

  // swizzled ds_read slot offsets (ushort units; row&7 == rl&7 for our rows)
  const int rb7 = rl & 7;
  const int slot0 = ((0 + hi) ^ rb7) << 3;   // k-slot 0
  const int slot1 = ((4 + hi) ^ rb7) << 3;   // k-slot 1

  f32x4 acc[8][4] = {};

  // ---- prologue: stage B(0), A(0), B(1) ----
  STG(pb,  0,  32768);           // B(0).h0
  STG(pb2, 0,  32768 + 8192);    // B(0).h1
  STG(pa,  0,  0);               // A(0).h0
  STG(pa2, 0,  8192);            // A(0).h1
  STG(pb,  64, 32768 + 16384);          // B(1).h0
  STG(pb2, 64, 32768 + 16384 + 8192);   // B(1).h1
  asm volatile("s_waitcnt vmcnt(4)" ::: "memory");
  asm volatile("s_barrier" ::: "memory");

  for (int it = 0; it < 32; ++it) {
    const int k0  = it * 128;
    const int kA1 = k0 + 64;                      // tile 2it+1
    const int kN0 = (k0 + 128) & (K_DIM - 1);     // tile 2it+2 (wrapped at end)
    const int kN1 = (k0 + 192) & (K_DIM - 1);     // tile 2it+3
    bf16x8 bfr[4][2];
    bf16x8 af00, af01, af10, af11;
    PHASE(0, 0, NOW, STG(pa,  kA1, 16384))                 // stage A(2it+1).h0
    PHASE(1, 0, NOW, STG(pa2, kA1, 16384 + 8192))          // A(2it+1).h1
    PHASE(2, 0, NOW, STG(pb,  kN0, 32768))                 // B(2it+2).h0
    PHASE(3, 0, VMW, STG(pb2, kN0, 32768 + 8192))          // B(2it+2).h1
    PHASE(0, 1, NOW, STG(pa,  kN0, 0))                     // A(2it+2).h0
    PHASE(1, 1, NOW, STG(pa2, kN0, 8192))                  // A(2it+2).h1
    PHASE(2, 1, NOW, STG(pb,  kN1, 32768 + 16384))         // B(2it+3).h0
    PHASE(3, 1, VMW, STG(pb2, kN1, 32768 + 16384 + 8192))  // B(2it+3).h1
  }

  #pragma unroll
  for (int m = 0; m < 8; ++m) {
    const int row = brow + wr * 128 + m * 16 + hi * 4;
    #pragma unroll
    for (int n = 0; n < 4; ++n) {
      const int col = bcol + wc * 64 + n * 16 + rl;
      #pragma unroll
      for (int r = 0; r < 4; ++r)
        C[(size_t)(row + r) * N_DIM + col] = acc[m][n][r];
    }
  }
}

extern "C" void kernel_launch(void* const* d_in, const int* in_sizes, int n_in,
                              void* d_out, int out_size, void* d_ws, size_t ws_size,
                              hipStream_t stream) {
  const float* x     = (const float*)d_in[0];
  const int*   idxp  = (const int*)d_in[1];
  const float* cb    = (const float*)d_in[2];
  const float* norms = (const float*)d_in[3];
  const float* rot   = (const float*)d_in[4];
  float* out = (float*)d_out;

  unsigned short* xb   = (unsigned short*)d_ws;                              // 64 MiB
  unsigned short* weff = (unsigned short*)((char*)d_ws + (size_t)67108864);  // 32 MiB

  k_prep<<<2048, 256, 0, stream>>>(x, xb, idxp, cb, norms, rot, weff);
  k_gemm<<<512, 512, 0, stream>>>(xb, weff, out);
}